// Round 4
// baseline (739.082 us; speedup 1.0000x reference)
//
#include <hip/hip_runtime.h>

#define T_DIM 32
#define N_NODES 10000
#define E_EDGES 160000
#define CAP 64                  // fixed bucket capacity per node (max in-deg ~42, Poisson(16))
#define CAPI4 (CAP / 2)         // int4 per row
#define EPAIR_N (N_NODES * CAP) // total int2 slots (5.12 MB)
#define NB_AGG 2500             // node-groups of 4 per t-slice (1 node per wave)
#define NBLK 2048               // k_layer grid
#define NBLK_XCD 256            // blocks per XCD (NBLK/8)

typedef float f32x4 __attribute__((ext_vector_type(4)));

// Fused: zero bucket array (pad slots must be (0,0.0f) -> FMA x0 exact),
// zero deg/cursor, detect index width.
// flag=1 -> int32 edge_index layout, flag=0 -> int64 (odd int32 words all 0).
__global__ __launch_bounds__(256) void k_prep(int4* __restrict__ epair4,
                                              float* __restrict__ deg,
                                              int* __restrict__ cursor,
                                              const int* __restrict__ ei,
                                              int* __restrict__ flag) {
    int i = blockIdx.x * 256 + threadIdx.x;
    if (i < EPAIR_N / 2) epair4[i] = make_int4(0, 0, 0, 0);
    if (i < N_NODES) { deg[i] = 0.f; cursor[i] = 0; }
    if (blockIdx.x == 0) {
        __shared__ int s_any;
        if (threadIdx.x == 0) s_any = 0;
        __syncthreads();
        if (ei[2 * threadIdx.x + 1] != 0) atomicOr(&s_any, 1);
        __syncthreads();
        if (threadIdx.x == 0) *flag = s_any;
    }
}

__device__ __forceinline__ int load_src(const int* ei, int e, int i32layout) {
    return i32layout ? ei[e] : ei[2 * e];
}
__device__ __forceinline__ int load_dst(const int* ei, int e, int i32layout) {
    return i32layout ? ei[E_EDGES + e] : ei[2 * E_EDGES + 2 * e];
}

// weighted in-degree only (count comes for free from the fill cursor)
__global__ __launch_bounds__(256) void k_deg(const int* __restrict__ ei,
                                             const float* __restrict__ ew,
                                             float* __restrict__ deg,
                                             const int* __restrict__ flag) {
    int e = blockIdx.x * 256 + threadIdx.x;
    int fl = *flag;
    if (e < E_EDGES) atomicAdd(&deg[load_dst(ei, e, fl)], ew[e]);
}

// scatter (src, norm) into fixed-capacity per-dst bucket; no scan needed.
__global__ __launch_bounds__(256) void k_fill(const int* __restrict__ ei,
                                              const float* __restrict__ ew,
                                              const float* __restrict__ deg,
                                              int* __restrict__ cursor,
                                              int2* __restrict__ epair,
                                              const int* __restrict__ flag) {
    int e = blockIdx.x * 256 + threadIdx.x;
    int fl = *flag;
    if (e < E_EDGES) {
        int s = load_src(ei, e, fl);
        int d = load_dst(ei, e, fl);
        float ds_ = deg[s], dd = deg[d];
        float nrm = ((ds_ > 0.f) ? rsqrtf(ds_) : 0.f) * ew[e] *
                    ((dd > 0.f) ? rsqrtf(dd) : 0.f);
        int slot = atomicAdd(&cursor[d], 1);
        if (slot < CAP) epair[d * CAP + slot] = make_int2(s, __float_as_int(nrm));
    }
}

#define GATHER8(M0, M1, M2, M3, H)                                  \
    H##0 = hb[(size_t)(M0).x * 64 + lane];                          \
    H##1 = hb[(size_t)(M0).z * 64 + lane];                          \
    H##2 = hb[(size_t)(M1).x * 64 + lane];                          \
    H##3 = hb[(size_t)(M1).z * 64 + lane];                          \
    H##4 = hb[(size_t)(M2).x * 64 + lane];                          \
    H##5 = hb[(size_t)(M2).z * 64 + lane];                          \
    H##6 = hb[(size_t)(M3).x * 64 + lane];                          \
    H##7 = hb[(size_t)(M3).z * 64 + lane];

#define FMA8(M0, M1, M2, M3, H)                                     \
    a0 = fmaf(__int_as_float((M0).y), H##0, a0);                    \
    a1 = fmaf(__int_as_float((M0).w), H##1, a1);                    \
    a2 = fmaf(__int_as_float((M1).y), H##2, a2);                    \
    a3 = fmaf(__int_as_float((M1).w), H##3, a3);                    \
    a0 = fmaf(__int_as_float((M2).y), H##4, a0);                    \
    a1 = fmaf(__int_as_float((M2).w), H##5, a1);                    \
    a2 = fmaf(__int_as_float((M3).y), H##6, a2);                    \
    a3 = fmaf(__int_as_float((M3).w), H##7, a3);

// load one W column element per lane: w<B><i> = W[(8B+i)*64 + lane]
#define WL8(B)                                                      \
    float w##B##0 = W[(8 * B + 0) * 64 + lane];                     \
    float w##B##1 = W[(8 * B + 1) * 64 + lane];                     \
    float w##B##2 = W[(8 * B + 2) * 64 + lane];                     \
    float w##B##3 = W[(8 * B + 3) * 64 + lane];                     \
    float w##B##4 = W[(8 * B + 4) * 64 + lane];                     \
    float w##B##5 = W[(8 * B + 5) * 64 + lane];                     \
    float w##B##6 = W[(8 * B + 6) * 64 + lane];                     \
    float w##B##7 = W[(8 * B + 7) * 64 + lane];

// opaque-ify so the compiler cannot rematerialize W as in-loop reloads
#define WPIN8(B)                                                    \
    asm volatile("" : "+v"(w##B##0), "+v"(w##B##1), "+v"(w##B##2),  \
                      "+v"(w##B##3), "+v"(w##B##4), "+v"(w##B##5),  \
                      "+v"(w##B##6), "+v"(w##B##7));

// epilogue: rows 4*IDX..4*IDX+3 via one b128 broadcast read, 4 chains
#define EPI4(IDX, WA, WB, WC, WD)                                   \
    {                                                               \
        f32x4 v = sr0[IDX];                                         \
        o0 = fmaf(v.x, WA, o0);                                     \
        o1 = fmaf(v.y, WB, o1);                                     \
        o2 = fmaf(v.z, WC, o2);                                     \
        o3 = fmaf(v.w, WD, o3);                                     \
    }

// Fused layer: out[t,n,:] = (relu?)( (A * hin)[t,n,:] @ W + bias ).
// R10 diagnosis: per-wave wall was ~10k cy/node vs ~500 cy of VALU issue --
// the rotation pipeline (SHIFT hA<-hB) drained vmcnt every chunk, so only
// ~1 chunk of gathers was ever in flight. Restructure: per node, issue ALL
// meta s_loads at loop top (one SMEM round), then ALL gathers (<=32, into
// 32 named regs, wave-uniform ceil8 guards), ONE waitcnt, then all FMAs.
// Zero register rotation. amdgpu_waves_per_eu(4,4) pins occupancy so the
// allocator keeps W in arch VGPRs instead of AGPR-spilling (R3 lesson:
// launch_bounds min-occupancy lets the backend target 8 waves and spill).
__global__ __attribute__((amdgpu_waves_per_eu(4, 4))) __launch_bounds__(256)
void k_layer(const float* __restrict__ hin,
             float* __restrict__ out,
             const int* __restrict__ cnts,
             const int4* __restrict__ emeta,
             const float* __restrict__ W,
             const float* __restrict__ bias,
             int relu) {
    __shared__ float srow[256];
    int lane = threadIdx.x & 63;
    int wave = threadIdx.x >> 6;
    // W[:,lane] in 64 named VGPRs, loaded once per block, pinned.
    WL8(0) WL8(1) WL8(2) WL8(3) WL8(4) WL8(5) WL8(6) WL8(7)
    WPIN8(0) WPIN8(1) WPIN8(2) WPIN8(3) WPIN8(4) WPIN8(5) WPIN8(6) WPIN8(7)
    float bv = bias[lane];

    int xcd = blockIdx.x & 7;
    int lb  = blockIdx.x >> 3;          // 0..255 within this XCD
#pragma unroll 1
    for (int i = 0; i < 4; ++i) {
        int t = xcd * 4 + i;
        const float* hb = hin + (size_t)t * (N_NODES * 64);
        float* ob = out + (size_t)t * (N_NODES * 64);
#pragma unroll 1
        for (int nb = lb; nb < NB_AGG; nb += NBLK_XCD) {
            int n = nb * 4 + wave;
            int un = __builtin_amdgcn_readfirstlane(n);     // wave-uniform -> SGPR
            int base = un * CAPI4;                          // int4 row base
            // meta for edges 0..31: unconditional uniform reads -> s_loads,
            // all issued together with cnt (single SMEM latency round)
            int4 m0  = emeta[base + 0];
            int4 m1  = emeta[base + 1];
            int4 m2  = emeta[base + 2];
            int4 m3  = emeta[base + 3];
            int4 m4  = emeta[base + 4];
            int4 m5  = emeta[base + 5];
            int4 m6  = emeta[base + 6];
            int4 m7  = emeta[base + 7];
            int4 m8  = emeta[base + 8];
            int4 m9  = emeta[base + 9];
            int4 m10 = emeta[base + 10];
            int4 m11 = emeta[base + 11];
            int4 m12 = emeta[base + 12];
            int4 m13 = emeta[base + 13];
            int4 m14 = emeta[base + 14];
            int4 m15 = emeta[base + 15];
            int cnt = cnts[un];                             // s_load
            if (cnt > CAP) cnt = CAP;
            int nE8 = (cnt + 7) & ~7;
            float a0 = 0.f, a1 = 0.f, a2 = 0.f, a3 = 0.f;
            if (nE8 > 0) {
                float hA0, hA1, hA2, hA3, hA4, hA5, hA6, hA7;
                float hB0, hB1, hB2, hB3, hB4, hB5, hB6, hB7;
                float hC0, hC1, hC2, hC3, hC4, hC5, hC6, hC7;
                float hD0, hD1, hD2, hD3, hD4, hD5, hD6, hD7;
                // ALL gathers first (up to 32 in flight), then all FMAs
                GATHER8(m0, m1, m2, m3, hA)
                if (nE8 > 8)  { GATHER8(m4, m5, m6, m7, hB) }
                if (nE8 > 16) { GATHER8(m8, m9, m10, m11, hC) }
                if (nE8 > 24) { GATHER8(m12, m13, m14, m15, hD) }
                FMA8(m0, m1, m2, m3, hA)
                if (nE8 > 8)  { FMA8(m4, m5, m6, m7, hB) }
                if (nE8 > 16) { FMA8(m8, m9, m10, m11, hC) }
                if (nE8 > 24) { FMA8(m12, m13, m14, m15, hD) }
                if (nE8 > 32) {                 // P(deg>32) ~ 1.4e-4: serial
#pragma unroll 1
                    for (int e = 32; e < nE8; e += 8) {
                        int4 r0 = emeta[base + (e >> 1) + 0];
                        int4 r1 = emeta[base + (e >> 1) + 1];
                        int4 r2 = emeta[base + (e >> 1) + 2];
                        int4 r3 = emeta[base + (e >> 1) + 3];
                        float x0, x1, x2, x3, x4, x5, x6, x7;
                        x0 = hb[(size_t)r0.x * 64 + lane];
                        x1 = hb[(size_t)r0.z * 64 + lane];
                        x2 = hb[(size_t)r1.x * 64 + lane];
                        x3 = hb[(size_t)r1.z * 64 + lane];
                        x4 = hb[(size_t)r2.x * 64 + lane];
                        x5 = hb[(size_t)r2.z * 64 + lane];
                        x6 = hb[(size_t)r3.x * 64 + lane];
                        x7 = hb[(size_t)r3.z * 64 + lane];
                        a0 = fmaf(__int_as_float(r0.y), x0, a0);
                        a1 = fmaf(__int_as_float(r0.w), x1, a1);
                        a2 = fmaf(__int_as_float(r1.y), x2, a2);
                        a3 = fmaf(__int_as_float(r1.w), x3, a3);
                        a0 = fmaf(__int_as_float(r2.y), x4, a0);
                        a1 = fmaf(__int_as_float(r2.w), x5, a1);
                        a2 = fmaf(__int_as_float(r3.y), x6, a2);
                        a3 = fmaf(__int_as_float(r3.w), x7, a3);
                    }
                }
            }
            srow[wave * 64 + lane] = (a0 + a1) + (a2 + a3);
            // same-wave LDS write->read: ordered by lgkmcnt, no barrier;
            // reads are all-lane-same-address broadcasts (bank-cheap)
            const f32x4* sr0 = (const f32x4*)(srow + wave * 64);
            float o0 = bv, o1 = 0.f, o2 = 0.f, o3 = 0.f;
            EPI4(0,  w00, w01, w02, w03)
            EPI4(1,  w04, w05, w06, w07)
            EPI4(2,  w10, w11, w12, w13)
            EPI4(3,  w14, w15, w16, w17)
            EPI4(4,  w20, w21, w22, w23)
            EPI4(5,  w24, w25, w26, w27)
            EPI4(6,  w30, w31, w32, w33)
            EPI4(7,  w34, w35, w36, w37)
            EPI4(8,  w40, w41, w42, w43)
            EPI4(9,  w44, w45, w46, w47)
            EPI4(10, w50, w51, w52, w53)
            EPI4(11, w54, w55, w56, w57)
            EPI4(12, w60, w61, w62, w63)
            EPI4(13, w64, w65, w66, w67)
            EPI4(14, w70, w71, w72, w73)
            EPI4(15, w74, w75, w76, w77)
            float of = (o0 + o1) + (o2 + o3);
            if (relu) of = fmaxf(of, 0.f);
            __builtin_nontemporal_store(of, &ob[(size_t)n * 64 + lane]);
        }
    }
}

// fallback-path copy (only used when workspace is too small for the h buffer)
__global__ __launch_bounds__(256) void k_copy(const f32x4* __restrict__ src,
                                              f32x4* __restrict__ dst, int n4) {
    int i = blockIdx.x * 256 + threadIdx.x;
    int stride = gridDim.x * 256;
    for (; i < n4; i += stride) dst[i] = src[i];
}

extern "C" void kernel_launch(void* const* d_in, const int* in_sizes, int n_in,
                              void* d_out, int out_size, void* d_ws, size_t ws_size,
                              hipStream_t stream) {
    const float* x  = (const float*)d_in[0];
    const int* ei   = (const int*)d_in[1];
    const float* ew = (const float*)d_in[2];
    const float* W1 = (const float*)d_in[3];
    const float* b1 = (const float*)d_in[4];
    const float* W2 = (const float*)d_in[5];
    const float* b2 = (const float*)d_in[6];
    float* out = (float*)d_out;
    (void)in_sizes; (void)n_in; (void)out_size;

    char* w = (char*)d_ws;
    size_t off = 0;
    auto alloc = [&](size_t bytes) {
        char* p = w + off;
        off = (off + bytes + 255) & ~(size_t)255;
        return p;
    };
    int*   flag   = (int*)  alloc(4);
    float* deg    = (float*)alloc(N_NODES * 4);
    int*   cursor = (int*)  alloc(N_NODES * 4);
    int2*  epair  = (int2*) alloc((size_t)EPAIR_N * 8);

    const size_t hbytes = (size_t)T_DIM * N_NODES * 64 * 4;   // 81.92 MB
    bool big_ws = (ws_size >= off + hbytes);
    float* hbuf = big_ws ? (float*)alloc(hbytes) : nullptr;

    // ---- bucketized edge build (no scan kernel) ----
    k_prep<<<(EPAIR_N / 2 + 255) / 256, 256, 0, stream>>>((int4*)epair, deg, cursor, ei, flag);
    k_deg<<<(E_EDGES + 255) / 256, 256, 0, stream>>>(ei, ew, deg, flag);
    k_fill<<<(E_EDGES + 255) / 256, 256, 0, stream>>>(ei, ew, deg, cursor, epair, flag);

    if (big_ws) {
        k_layer<<<NBLK, 256, 0, stream>>>(x, hbuf, cursor, (const int4*)epair, W1, b1, 1);
        k_layer<<<NBLK, 256, 0, stream>>>(hbuf, out, cursor, (const int4*)epair, W2, b2, 0);
    } else {
        // xscr reuses d_in[0]: x fully consumed by layer 1; harness restores
        // d_in from pristine before every launch.
        float* xscr = (float*)d_in[0];
        k_layer<<<NBLK, 256, 0, stream>>>(x, out, cursor, (const int4*)epair, W1, b1, 1);
        k_layer<<<NBLK, 256, 0, stream>>>(out, xscr, cursor, (const int4*)epair, W2, b2, 0);
        int n4 = (int)(hbytes / 16);
        k_copy<<<2048, 256, 0, stream>>>((const f32x4*)xscr, (f32x4*)out, n4);
    }
}

// Round 6
// 498.628 us; speedup vs baseline: 1.4822x; 1.4822x over previous
//
#include <hip/hip_runtime.h>

#define T_DIM 32
#define N_NODES 10000
#define E_EDGES 160000
#define CAP 64                  // fixed bucket capacity per node (max in-deg ~42, Poisson(16))
#define CAPI4 (CAP / 2)         // int4 per row
#define EPAIR_N (N_NODES * CAP) // total int2 slots (5.12 MB)
#define NB_AGG 2500             // node-groups of 4 per t-slice (1 node per wave)
#define NBLK 2048               // grid
#define NBLK_XCD 256            // blocks per XCD (NBLK/8)
#define NROW_TILES 5000         // (T*N)/64 row tiles for k_dense

typedef float f32x4 __attribute__((ext_vector_type(4)));

// Fused: zero bucket array (pad slots must be (0,0.0f) -> FMA x0 exact),
// zero deg/cursor, detect index width.
// flag=1 -> int32 edge_index layout, flag=0 -> int64 (odd int32 words all 0).
__global__ __launch_bounds__(256) void k_prep(int4* __restrict__ epair4,
                                              float* __restrict__ deg,
                                              int* __restrict__ cursor,
                                              const int* __restrict__ ei,
                                              int* __restrict__ flag) {
    int i = blockIdx.x * 256 + threadIdx.x;
    if (i < EPAIR_N / 2) epair4[i] = make_int4(0, 0, 0, 0);
    if (i < N_NODES) { deg[i] = 0.f; cursor[i] = 0; }
    if (blockIdx.x == 0) {
        __shared__ int s_any;
        if (threadIdx.x == 0) s_any = 0;
        __syncthreads();
        if (ei[2 * threadIdx.x + 1] != 0) atomicOr(&s_any, 1);
        __syncthreads();
        if (threadIdx.x == 0) *flag = s_any;
    }
}

__device__ __forceinline__ int load_src(const int* ei, int e, int i32layout) {
    return i32layout ? ei[e] : ei[2 * e];
}
__device__ __forceinline__ int load_dst(const int* ei, int e, int i32layout) {
    return i32layout ? ei[E_EDGES + e] : ei[2 * E_EDGES + 2 * e];
}

// weighted in-degree only (count comes for free from the fill cursor)
__global__ __launch_bounds__(256) void k_deg(const int* __restrict__ ei,
                                             const float* __restrict__ ew,
                                             float* __restrict__ deg,
                                             const int* __restrict__ flag) {
    int e = blockIdx.x * 256 + threadIdx.x;
    int fl = *flag;
    if (e < E_EDGES) atomicAdd(&deg[load_dst(ei, e, fl)], ew[e]);
}

// scatter (src, norm) into fixed-capacity per-dst bucket; no scan needed.
__global__ __launch_bounds__(256) void k_fill(const int* __restrict__ ei,
                                              const float* __restrict__ ew,
                                              const float* __restrict__ deg,
                                              int* __restrict__ cursor,
                                              int2* __restrict__ epair,
                                              const int* __restrict__ flag) {
    int e = blockIdx.x * 256 + threadIdx.x;
    int fl = *flag;
    if (e < E_EDGES) {
        int s = load_src(ei, e, fl);
        int d = load_dst(ei, e, fl);
        float ds_ = deg[s], dd = deg[d];
        float nrm = ((ds_ > 0.f) ? rsqrtf(ds_) : 0.f) * ew[e] *
                    ((dd > 0.f) ? rsqrtf(dd) : 0.f);
        int slot = atomicAdd(&cursor[d], 1);
        if (slot < CAP) epair[d * CAP + slot] = make_int2(s, __float_as_int(nrm));
    }
}

// ---------------------------------------------------------------------------
// k_agg: g[t,n,:] = sum_e nrm_e * h[t,src_e,:]   (pure aggregation, no W)
// R11: lane-partitioned gathers. lane = (es = lane>>4, fq = lane&15).
// One global_load_dwordx4 with per-lane addresses fetches edges e..e+3 of the
// node: 4 rows x 256B = 1KB per instruction (4x fewer VMEM instrs than the
// uniform-base form). ~30 VGPRs -> genuine 8 waves/SIMD occupancy; goal is
// raising average outstanding gathers/CU past the latency-hiding knee.
// Pad slots are (0,0.0f) -> FMA x0 exact, so loop bound is uniform ceil4.
// Cross-lane reduce over the 4 edge-slot groups via shfl_xor(16,32).
// ---------------------------------------------------------------------------
__global__ __launch_bounds__(256) void k_agg(const float* __restrict__ hin,
                                             float* __restrict__ gout,
                                             const int* __restrict__ cnts,
                                             const int2* __restrict__ epair) {
    int lane = threadIdx.x & 63;
    int wave = threadIdx.x >> 6;
    int es = lane >> 4;                 // edge slot 0..3
    int fq = lane & 15;                 // f-quad 0..15

    int xcd = blockIdx.x & 7;
    int lb  = blockIdx.x >> 3;          // 0..255 within this XCD
#pragma unroll 1
    for (int i = 0; i < 4; ++i) {
        int t = xcd * 4 + i;
        const f32x4* hb4 = (const f32x4*)(hin + (size_t)t * (N_NODES * 64));
        f32x4* gb4 = (f32x4*)(gout + (size_t)t * (N_NODES * 64));
#pragma unroll 1
        for (int nb = lb; nb < NB_AGG; nb += NBLK_XCD) {
            int n = nb * 4 + wave;
            int un = __builtin_amdgcn_readfirstlane(n);     // uniform -> SGPR
            int cnt = cnts[un];                             // s_load
            if (cnt > CAP) cnt = CAP;
            int mE = (cnt + 3) & ~3;                        // ceil4, uniform
            const int2* mrow = epair + (size_t)un * CAP;    // uniform base
            f32x4 acc; acc.x = 0.f; acc.y = 0.f; acc.z = 0.f; acc.w = 0.f;
            if (mE > 0) {
                int2 mcur = mrow[es];                       // edge e=0+es meta
                int e = 0;
                for (;;) {
                    // gather: 4 rows x 256B in ONE instruction (per-lane addr)
                    f32x4 h = hb4[(size_t)(unsigned)mcur.x * 16 + fq];
                    e += 4;
                    bool more = e < mE;                     // uniform branch
                    int2 mnext = make_int2(0, 0);
                    if (more) mnext = mrow[e + es];         // prefetch meta
                    float w = __int_as_float(mcur.y);
                    acc.x = fmaf(w, h.x, acc.x);
                    acc.y = fmaf(w, h.y, acc.y);
                    acc.z = fmaf(w, h.z, acc.z);
                    acc.w = fmaf(w, h.w, acc.w);
                    if (!more) break;
                    mcur = mnext;
                }
            }
            // reduce over the 4 edge-slot groups (lanes l, l^16, l^32, l^48)
            acc.x += __shfl_xor(acc.x, 16);
            acc.y += __shfl_xor(acc.y, 16);
            acc.z += __shfl_xor(acc.z, 16);
            acc.w += __shfl_xor(acc.w, 16);
            acc.x += __shfl_xor(acc.x, 32);
            acc.y += __shfl_xor(acc.y, 32);
            acc.z += __shfl_xor(acc.z, 32);
            acc.w += __shfl_xor(acc.w, 32);
            if (lane < 16)                                  // one 256B row store
                gb4[(size_t)un * 16 + fq] = acc;
        }
    }
}

// ---------------------------------------------------------------------------
// k_dense: z[row,:] = (relu?)( y[row,:] @ W + b ), rows = T*N, tiled 64/block.
// No per-lane W registers (the 64-VGPR wall): W lives transposed+padded in
// LDS, read ONCE per k-quad per wave and shared across 16 rows; y tile staged
// in LDS, consumed as all-lane broadcast b128 reads (bank-free). Row-exclusive
// tiles -> in-place (yin==zout) safe.
// ---------------------------------------------------------------------------
__global__ __launch_bounds__(256) void k_dense(const float* __restrict__ yin,
                                               float* __restrict__ zout,
                                               const float* __restrict__ W,
                                               const float* __restrict__ bias,
                                               int relu) {
    __shared__ float sWt[64 * 65];      // sWt[f*65+k] = W[k*64+f] (pad 65: 2-way banks)
    __shared__ float sy[64 * 64];       // 64-row y tile (16 KB)
    int tid = threadIdx.x;
    int lane = tid & 63;
    int wave = tid >> 6;
#pragma unroll
    for (int j = 0; j < 16; ++j) {
        int idx = j * 256 + tid;
        sWt[(idx & 63) * 65 + (idx >> 6)] = W[idx];
    }
    float bv = bias[lane];
    __syncthreads();

    f32x4* sy4 = (f32x4*)sy;
#pragma unroll 1
    for (int rt = blockIdx.x; rt < NROW_TILES; rt += NBLK) {
        const f32x4* ysrc = (const f32x4*)(yin + (size_t)rt * (64 * 64));
        f32x4 s0 = ysrc[tid];
        f32x4 s1 = ysrc[tid + 256];
        f32x4 s2 = ysrc[tid + 512];
        f32x4 s3 = ysrc[tid + 768];
        __syncthreads();                // prior tile fully consumed
        sy4[tid]       = s0;
        sy4[tid + 256] = s1;
        sy4[tid + 512] = s2;
        sy4[tid + 768] = s3;
        __syncthreads();

        const float* syw = sy + wave * (16 * 64);   // this wave's 16 rows
        float acc[16];
#pragma unroll
        for (int r = 0; r < 16; ++r) acc[r] = bv;
#pragma unroll
        for (int k4 = 0; k4 < 16; ++k4) {
            f32x4 wv = *(const f32x4*)(&sWt[lane * 65 + k4 * 4]); // shared W read
#pragma unroll
            for (int r = 0; r < 16; ++r) {
                f32x4 yv = *(const f32x4*)(&syw[r * 64 + k4 * 4]); // broadcast
                acc[r] = fmaf(yv.x, wv.x, acc[r]);
                acc[r] = fmaf(yv.y, wv.y, acc[r]);
                acc[r] = fmaf(yv.z, wv.z, acc[r]);
                acc[r] = fmaf(yv.w, wv.w, acc[r]);
            }
        }
        size_t rowb = (size_t)rt * 64 + wave * 16;
#pragma unroll
        for (int r = 0; r < 16; ++r) {
            float o = acc[r];
            if (relu) o = fmaxf(o, 0.f);
            __builtin_nontemporal_store(o, &zout[(rowb + r) * 64 + lane]);
        }
    }
}

extern "C" void kernel_launch(void* const* d_in, const int* in_sizes, int n_in,
                              void* d_out, int out_size, void* d_ws, size_t ws_size,
                              hipStream_t stream) {
    const float* x  = (const float*)d_in[0];
    const int* ei   = (const int*)d_in[1];
    const float* ew = (const float*)d_in[2];
    const float* W1 = (const float*)d_in[3];
    const float* b1 = (const float*)d_in[4];
    const float* W2 = (const float*)d_in[5];
    const float* b2 = (const float*)d_in[6];
    float* out = (float*)d_out;
    (void)in_sizes; (void)n_in; (void)out_size;

    char* w = (char*)d_ws;
    size_t off = 0;
    auto alloc = [&](size_t bytes) {
        char* p = w + off;
        off = (off + bytes + 255) & ~(size_t)255;
        return p;
    };
    int*   flag   = (int*)  alloc(4);
    float* deg    = (float*)alloc(N_NODES * 4);
    int*   cursor = (int*)  alloc(N_NODES * 4);
    int2*  epair  = (int2*) alloc((size_t)EPAIR_N * 8);

    const size_t hbytes = (size_t)T_DIM * N_NODES * 64 * 4;   // 81.92 MB
    bool big_ws = (ws_size >= off + hbytes);
    float* buf = big_ws ? (float*)alloc(hbytes) : nullptr;

    // ---- bucketized edge build ----
    k_prep<<<(EPAIR_N / 2 + 255) / 256, 256, 0, stream>>>((int4*)epair, deg, cursor, ei, flag);
    k_deg<<<(E_EDGES + 255) / 256, 256, 0, stream>>>(ei, ew, deg, flag);
    k_fill<<<(E_EDGES + 255) / 256, 256, 0, stream>>>(ei, ew, deg, cursor, epair, flag);

    if (big_ws) {
        // S1: g1 = A x -> buf; S2: h = relu(g1 W1+b1) -> out;
        // S3: g2 = A h -> buf; S4: out = g2 W2+b2 -> out.  x never written.
        k_agg<<<NBLK, 256, 0, stream>>>(x, buf, cursor, epair);
        k_dense<<<NBLK, 256, 0, stream>>>(buf, out, W1, b1, 1);
        k_agg<<<NBLK, 256, 0, stream>>>(out, buf, cursor, epair);
        k_dense<<<NBLK, 256, 0, stream>>>(buf, out, W2, b2, 0);
    } else {
        // small-ws path: route intermediates through d_out and d_in[0]
        // (x fully consumed by S1; harness restores inputs each launch).
        float* xscr = (float*)d_in[0];
        k_agg<<<NBLK, 256, 0, stream>>>(x, out, cursor, epair);       // g1 -> out
        k_dense<<<NBLK, 256, 0, stream>>>(out, xscr, W1, b1, 1);      // h  -> xscr
        k_agg<<<NBLK, 256, 0, stream>>>(xscr, out, cursor, epair);    // g2 -> out
        k_dense<<<NBLK, 256, 0, stream>>>(out, out, W2, b2, 0);       // in-place
    }
}

// Round 7
// 497.356 us; speedup vs baseline: 1.4860x; 1.0026x over previous
//
#include <hip/hip_runtime.h>

#define T_DIM 32
#define N_NODES 10000
#define E_EDGES 160000
#define CAP 64                  // fixed bucket capacity per node (max in-deg ~42, Poisson(16))
#define CAPI4 (CAP / 2)         // int4 per row
#define EPAIR_N (N_NODES * CAP) // total int2 slots (5.12 MB)
#define NB_AGG 2500             // node-groups of 4 per t-slice (1 node per wave)
#define NBLK 2048               // grid
#define NBLK_XCD 256            // blocks per XCD (NBLK/8)
#define NROW_TILES 5000         // (T*N)/64 row tiles for k_dense

typedef float f32x4 __attribute__((ext_vector_type(4)));

// Fused: zero bucket array (pad slots must be (0,0.0f) -> FMA x0 exact),
// zero deg/cursor, detect index width.
// flag=1 -> int32 edge_index layout, flag=0 -> int64 (odd int32 words all 0).
__global__ __launch_bounds__(256) void k_prep(int4* __restrict__ epair4,
                                              float* __restrict__ deg,
                                              int* __restrict__ cursor,
                                              const int* __restrict__ ei,
                                              int* __restrict__ flag) {
    int i = blockIdx.x * 256 + threadIdx.x;
    if (i < EPAIR_N / 2) epair4[i] = make_int4(0, 0, 0, 0);
    if (i < N_NODES) { deg[i] = 0.f; cursor[i] = 0; }
    if (blockIdx.x == 0) {
        __shared__ int s_any;
        if (threadIdx.x == 0) s_any = 0;
        __syncthreads();
        if (ei[2 * threadIdx.x + 1] != 0) atomicOr(&s_any, 1);
        __syncthreads();
        if (threadIdx.x == 0) *flag = s_any;
    }
}

__device__ __forceinline__ int load_src(const int* ei, int e, int i32layout) {
    return i32layout ? ei[e] : ei[2 * e];
}
__device__ __forceinline__ int load_dst(const int* ei, int e, int i32layout) {
    return i32layout ? ei[E_EDGES + e] : ei[2 * E_EDGES + 2 * e];
}

// weighted in-degree only (count comes for free from the fill cursor)
__global__ __launch_bounds__(256) void k_deg(const int* __restrict__ ei,
                                             const float* __restrict__ ew,
                                             float* __restrict__ deg,
                                             const int* __restrict__ flag) {
    int e = blockIdx.x * 256 + threadIdx.x;
    int fl = *flag;
    if (e < E_EDGES) atomicAdd(&deg[load_dst(ei, e, fl)], ew[e]);
}

// scatter (src, norm) into fixed-capacity per-dst bucket; no scan needed.
__global__ __launch_bounds__(256) void k_fill(const int* __restrict__ ei,
                                              const float* __restrict__ ew,
                                              const float* __restrict__ deg,
                                              int* __restrict__ cursor,
                                              int2* __restrict__ epair,
                                              const int* __restrict__ flag) {
    int e = blockIdx.x * 256 + threadIdx.x;
    int fl = *flag;
    if (e < E_EDGES) {
        int s = load_src(ei, e, fl);
        int d = load_dst(ei, e, fl);
        float ds_ = deg[s], dd = deg[d];
        float nrm = ((ds_ > 0.f) ? rsqrtf(ds_) : 0.f) * ew[e] *
                    ((dd > 0.f) ? rsqrtf(dd) : 0.f);
        int slot = atomicAdd(&cursor[d], 1);
        if (slot < CAP) epair[d * CAP + slot] = make_int2(s, __float_as_int(nrm));
    }
}

// one int4 of meta = 2 edges: (.x=src0,.y=nrm0,.z=src1,.w=nrm1)
#define LD2(M, H0, H1)                                              \
    H0 = hb[(size_t)(unsigned)(M).x * 64 + lane];                   \
    H1 = hb[(size_t)(unsigned)(M).z * 64 + lane];

#define FM2(M, H0, H1, A0, A1)                                      \
    A0 = fmaf(__int_as_float((M).y), H0, A0);                       \
    A1 = fmaf(__int_as_float((M).w), H1, A1);

// ---------------------------------------------------------------------------
// k_agg: g[t,n,:] = sum_e nrm_e * h[t,src_e,:]   (pure aggregation, no W)
// R12: MLP-first restructure. R6 post-mortem: one gather in flight per wave
// (gather -> immediate FMA, meta on the vmem path) -> ~400cy exposed per
// 4-edge chunk, nothing saturated. Now: meta via wave-uniform s_load batches
// (SGPR, zero vmem, SALU addresses), then ALL of the node's gathers issued
// back-to-back (16 or 24 global_load_dword, each one 256B segment), ONE
// incremental-waitcnt FMA block. 64-96 cache lines in flight PER WAVE.
// Two uniform tiers (cnt<=16 / <=24) + rare serial tail (P(deg>24)~2%).
// Pad slots are (0,0.0f) -> FMA x0 exact. Nontemporal store keeps the
// 2.56MB/t output stream from evicting the L2-resident h slice.
// ---------------------------------------------------------------------------
__global__ __launch_bounds__(256) void k_agg(const float* __restrict__ hin,
                                             float* __restrict__ gout,
                                             const int* __restrict__ cnts,
                                             const int4* __restrict__ emeta) {
    int lane = threadIdx.x & 63;
    int wave = threadIdx.x >> 6;
    int xcd = blockIdx.x & 7;
    int lb  = blockIdx.x >> 3;          // 0..255 within this XCD
#pragma unroll 1
    for (int i = 0; i < 4; ++i) {
        int t = xcd * 4 + i;
        const float* hb = hin + (size_t)t * (N_NODES * 64);
        float* ob = gout + (size_t)t * (N_NODES * 64);
#pragma unroll 1
        for (int nb = lb; nb < NB_AGG; nb += NBLK_XCD) {
            int n = nb * 4 + wave;
            int un = __builtin_amdgcn_readfirstlane(n);     // wave-uniform -> SGPR
            int base = un * CAPI4;                          // int4 row base
            int cnt = cnts[un];                             // s_load
            if (cnt > CAP) cnt = CAP;
            // meta edges 0..15: uniform -> s_load_dwordx16 x2, one SMEM round
            int4 m0 = emeta[base + 0];
            int4 m1 = emeta[base + 1];
            int4 m2 = emeta[base + 2];
            int4 m3 = emeta[base + 3];
            int4 m4 = emeta[base + 4];
            int4 m5 = emeta[base + 5];
            int4 m6 = emeta[base + 6];
            int4 m7 = emeta[base + 7];
            float a0 = 0.f, a1 = 0.f, a2 = 0.f, a3 = 0.f;
            if (cnt <= 16) {                                // 57% of nodes
                float h0, h1, h2, h3, h4, h5, h6, h7;
                float h8, h9, h10, h11, h12, h13, h14, h15;
                LD2(m0, h0, h1)   LD2(m1, h2, h3)
                LD2(m2, h4, h5)   LD2(m3, h6, h7)
                LD2(m4, h8, h9)   LD2(m5, h10, h11)
                LD2(m6, h12, h13) LD2(m7, h14, h15)
                FM2(m0, h0, h1, a0, a1)    FM2(m1, h2, h3, a2, a3)
                FM2(m2, h4, h5, a0, a1)    FM2(m3, h6, h7, a2, a3)
                FM2(m4, h8, h9, a0, a1)    FM2(m5, h10, h11, a2, a3)
                FM2(m6, h12, h13, a0, a1)  FM2(m7, h14, h15, a2, a3)
            } else {
                int4 m8  = emeta[base + 8];
                int4 m9  = emeta[base + 9];
                int4 m10 = emeta[base + 10];
                int4 m11 = emeta[base + 11];
                float h0, h1, h2, h3, h4, h5, h6, h7;
                float h8, h9, h10, h11, h12, h13, h14, h15;
                float h16, h17, h18, h19, h20, h21, h22, h23;
                LD2(m0, h0, h1)    LD2(m1, h2, h3)
                LD2(m2, h4, h5)    LD2(m3, h6, h7)
                LD2(m4, h8, h9)    LD2(m5, h10, h11)
                LD2(m6, h12, h13)  LD2(m7, h14, h15)
                LD2(m8, h16, h17)  LD2(m9, h18, h19)
                LD2(m10, h20, h21) LD2(m11, h22, h23)
                FM2(m0, h0, h1, a0, a1)     FM2(m1, h2, h3, a2, a3)
                FM2(m2, h4, h5, a0, a1)     FM2(m3, h6, h7, a2, a3)
                FM2(m4, h8, h9, a0, a1)     FM2(m5, h10, h11, a2, a3)
                FM2(m6, h12, h13, a0, a1)   FM2(m7, h14, h15, a2, a3)
                FM2(m8, h16, h17, a0, a1)   FM2(m9, h18, h19, a2, a3)
                FM2(m10, h20, h21, a0, a1)  FM2(m11, h22, h23, a2, a3)
                if (cnt > 24) {             // P ~2%: serial 2-edge steps
#pragma unroll 1
                    for (int e = 24; e < cnt; e += 2) {
                        int4 mt = emeta[base + (e >> 1)];
                        float x0, x1;
                        LD2(mt, x0, x1)
                        FM2(mt, x0, x1, a0, a1)
                    }
                }
            }
            float s = (a0 + a1) + (a2 + a3);
            __builtin_nontemporal_store(s, &ob[(size_t)un * 64 + lane]);
        }
    }
}

// ---------------------------------------------------------------------------
// k_dense: z[row,:] = (relu?)( y[row,:] @ W + b ), rows = T*N, tiled 64/block.
// No per-lane W registers (the 64-VGPR wall): W lives transposed+padded in
// LDS, read ONCE per k-quad per wave and shared across 16 rows; y tile staged
// in LDS, consumed as all-lane broadcast b128 reads (bank-free). Row-exclusive
// tiles -> in-place (yin==zout) safe.  [R6: ~27us each, near HBM floor]
// ---------------------------------------------------------------------------
__global__ __launch_bounds__(256) void k_dense(const float* __restrict__ yin,
                                               float* __restrict__ zout,
                                               const float* __restrict__ W,
                                               const float* __restrict__ bias,
                                               int relu) {
    __shared__ float sWt[64 * 65];      // sWt[f*65+k] = W[k*64+f] (pad 65: 2-way banks)
    __shared__ float sy[64 * 64];       // 64-row y tile (16 KB)
    int tid = threadIdx.x;
    int lane = tid & 63;
    int wave = tid >> 6;
#pragma unroll
    for (int j = 0; j < 16; ++j) {
        int idx = j * 256 + tid;
        sWt[(idx & 63) * 65 + (idx >> 6)] = W[idx];
    }
    float bv = bias[lane];
    __syncthreads();

    f32x4* sy4 = (f32x4*)sy;
#pragma unroll 1
    for (int rt = blockIdx.x; rt < NROW_TILES; rt += NBLK) {
        const f32x4* ysrc = (const f32x4*)(yin + (size_t)rt * (64 * 64));
        f32x4 s0 = ysrc[tid];
        f32x4 s1 = ysrc[tid + 256];
        f32x4 s2 = ysrc[tid + 512];
        f32x4 s3 = ysrc[tid + 768];
        __syncthreads();                // prior tile fully consumed
        sy4[tid]       = s0;
        sy4[tid + 256] = s1;
        sy4[tid + 512] = s2;
        sy4[tid + 768] = s3;
        __syncthreads();

        const float* syw = sy + wave * (16 * 64);   // this wave's 16 rows
        float acc[16];
#pragma unroll
        for (int r = 0; r < 16; ++r) acc[r] = bv;
#pragma unroll
        for (int k4 = 0; k4 < 16; ++k4) {
            f32x4 wv = *(const f32x4*)(&sWt[lane * 65 + k4 * 4]); // shared W read
#pragma unroll
            for (int r = 0; r < 16; ++r) {
                f32x4 yv = *(const f32x4*)(&syw[r * 64 + k4 * 4]); // broadcast
                acc[r] = fmaf(yv.x, wv.x, acc[r]);
                acc[r] = fmaf(yv.y, wv.y, acc[r]);
                acc[r] = fmaf(yv.z, wv.z, acc[r]);
                acc[r] = fmaf(yv.w, wv.w, acc[r]);
            }
        }
        size_t rowb = (size_t)rt * 64 + wave * 16;
#pragma unroll
        for (int r = 0; r < 16; ++r) {
            float o = acc[r];
            if (relu) o = fmaxf(o, 0.f);
            __builtin_nontemporal_store(o, &zout[(rowb + r) * 64 + lane]);
        }
    }
}

extern "C" void kernel_launch(void* const* d_in, const int* in_sizes, int n_in,
                              void* d_out, int out_size, void* d_ws, size_t ws_size,
                              hipStream_t stream) {
    const float* x  = (const float*)d_in[0];
    const int* ei   = (const int*)d_in[1];
    const float* ew = (const float*)d_in[2];
    const float* W1 = (const float*)d_in[3];
    const float* b1 = (const float*)d_in[4];
    const float* W2 = (const float*)d_in[5];
    const float* b2 = (const float*)d_in[6];
    float* out = (float*)d_out;
    (void)in_sizes; (void)n_in; (void)out_size;

    char* w = (char*)d_ws;
    size_t off = 0;
    auto alloc = [&](size_t bytes) {
        char* p = w + off;
        off = (off + bytes + 255) & ~(size_t)255;
        return p;
    };
    int*   flag   = (int*)  alloc(4);
    float* deg    = (float*)alloc(N_NODES * 4);
    int*   cursor = (int*)  alloc(N_NODES * 4);
    int2*  epair  = (int2*) alloc((size_t)EPAIR_N * 8);

    const size_t hbytes = (size_t)T_DIM * N_NODES * 64 * 4;   // 81.92 MB
    bool big_ws = (ws_size >= off + hbytes);
    float* buf = big_ws ? (float*)alloc(hbytes) : nullptr;

    // ---- bucketized edge build ----
    k_prep<<<(EPAIR_N / 2 + 255) / 256, 256, 0, stream>>>((int4*)epair, deg, cursor, ei, flag);
    k_deg<<<(E_EDGES + 255) / 256, 256, 0, stream>>>(ei, ew, deg, flag);
    k_fill<<<(E_EDGES + 255) / 256, 256, 0, stream>>>(ei, ew, deg, cursor, epair, flag);

    if (big_ws) {
        // S1: g1 = A x -> buf; S2: h = relu(g1 W1+b1) -> out;
        // S3: g2 = A h -> buf; S4: out = g2 W2+b2 -> out.  x never written.
        k_agg<<<NBLK, 256, 0, stream>>>(x, buf, cursor, (const int4*)epair);
        k_dense<<<NBLK, 256, 0, stream>>>(buf, out, W1, b1, 1);
        k_agg<<<NBLK, 256, 0, stream>>>(out, buf, cursor, (const int4*)epair);
        k_dense<<<NBLK, 256, 0, stream>>>(buf, out, W2, b2, 0);
    } else {
        // small-ws path: route intermediates through d_out and d_in[0]
        // (x fully consumed by S1; harness restores inputs each launch).
        float* xscr = (float*)d_in[0];
        k_agg<<<NBLK, 256, 0, stream>>>(x, out, cursor, (const int4*)epair);   // g1 -> out
        k_dense<<<NBLK, 256, 0, stream>>>(out, xscr, W1, b1, 1);               // h  -> xscr
        k_agg<<<NBLK, 256, 0, stream>>>(xscr, out, cursor, (const int4*)epair);// g2 -> out
        k_dense<<<NBLK, 256, 0, stream>>>(out, out, W2, b2, 0);                // in-place
    }
}